// Round 1
// baseline (359.006 us; speedup 1.0000x reference)
//
#include <hip/hip_runtime.h>

// Problem geometry
#define NELEM (16 * 16 * 512 * 64)   // 8,388,608 elements of NEW_SHAPE
// weight index: rc = idx>>15 (c*16+r), i = (idx>>6)&511, j = idx&63
// d2 = i>>3, slice s = i&7 (MSB-first => shift = (7-s)*2)

// ---- mask dtype detection ------------------------------------------------
// active_mask is bool in the reference. The harness may ship it as:
//   mode 0: 1 byte per element (np.bool_)
//   mode 1: int32 0/1
//   mode 2: float32 0.0/1.0
// Distinguish by scanning raw 32-bit words:
//   - byte-bools  -> words made of bytes {0,1}: many values > 1, never 0x3F800000
//   - int32 0/1   -> all words <= 1
//   - float 0/1   -> words in {0, 0x3F800000}
__global__ __launch_bounds__(256) void detect_mask_kernel(
    const unsigned int* __restrict__ m, int* __restrict__ flag)
{
    __shared__ int sawBig, sawFloat;
    if (threadIdx.x == 0) { sawBig = 0; sawFloat = 0; }
    __syncthreads();
    int big = 0, flt = 0;
    for (int k = threadIdx.x; k < 4096; k += 256) {
        unsigned int v = m[k];
        if (v == 0x3F800000u) flt = 1;
        else if (v > 1u)      big = 1;
    }
    if (big) atomicOr(&sawBig, 1);
    if (flt) atomicOr(&sawFloat, 1);
    __syncthreads();
    if (threadIdx.x == 0) {
        int f;
        if (sawFloat)     f = 2;  // float32 mask
        else if (sawBig)  f = 0;  // byte mask
        else              f = 1;  // int32 mask (all-zero case: any mode works)
        *flag = f;
    }
}

// branchless select of one lane of a float4 by code c in {0,1,2,3}
__device__ __forceinline__ float sel4(float4 v, int c) {
    return (c & 1) ? ((c & 2) ? v.w : v.y)
                   : ((c & 2) ? v.z : v.x);
}

__global__ __launch_bounds__(256) void w2g_main_kernel(
    const float*  __restrict__ input,     // (16,16,64,64)
    const float4* __restrict__ meanG,     // (NELEM, 4) as float4
    const float4* __restrict__ sigG,      // (NELEM, 4) as float4
    const float*  __restrict__ eps,       // (NELEM)
    const unsigned char* __restrict__ mask8,
    const int*    __restrict__ mask32,
    const float*  __restrict__ maskf,
    const int*    __restrict__ flag,
    float*        __restrict__ out)       // 4 * NELEM: [Gp*am][Gn*am][Gp*!am][Gn*!am]
{
    int idx = blockIdx.x * blockDim.x + threadIdx.x;   // grid exactly covers NELEM

    int j  = idx & 63;
    int i  = (idx >> 6) & 511;
    int rc = idx >> 15;
    int shift = (7 - (i & 7)) * 2;

    // weight (4 MB array, L2-resident; coalesced across j)
    float w = input[(rc << 12) | ((i >> 3) << 6) | j];
    int wi = (int)w;                       // exact: integers in [-32767, 32767]
    int p = wi > 0 ?  wi : 0;
    int n = wi < 0 ? -wi : 0;
    int cp = (p >> shift) & 3;
    int cn = (n >> shift) & 3;

    float4 m4 = meanG[idx];                // 16B coalesced
    float4 s4 = sigG[idx];                 // 16B coalesced
    float  e  = eps[idx];

    float Gp = sel4(m4, cp) + e * sel4(s4, cp);
    float Gn = sel4(m4, cn) + e * sel4(s4, cn);

    int f = *flag;                         // uniform, cached broadcast
    bool am;
    if (f == 1)      am = (mask32[idx] != 0);
    else if (f == 0) am = (mask8[idx]  != 0);
    else             am = (maskf[idx]  != 0.0f);

    out[idx]             = am ? Gp : 0.0f;
    out[NELEM + idx]     = am ? Gn : 0.0f;
    out[2 * NELEM + idx] = am ? 0.0f : Gp;
    out[3 * NELEM + idx] = am ? 0.0f : Gn;
}

extern "C" void kernel_launch(void* const* d_in, const int* in_sizes, int n_in,
                              void* d_out, int out_size, void* d_ws, size_t ws_size,
                              hipStream_t stream) {
    const float*  input = (const float*) d_in[0];
    const float4* meanG = (const float4*)d_in[1];
    const float4* sigG  = (const float4*)d_in[2];
    const float*  eps   = (const float*) d_in[3];
    const void*   mask  = d_in[4];
    int* flag = (int*)d_ws;

    detect_mask_kernel<<<1, 256, 0, stream>>>((const unsigned int*)mask, flag);

    int threads = 256;
    int blocks  = NELEM / threads;         // 32768
    w2g_main_kernel<<<blocks, threads, 0, stream>>>(
        input, meanG, sigG, eps,
        (const unsigned char*)mask, (const int*)mask, (const float*)mask,
        flag, (float*)d_out);
}

// Round 6
// 339.794 us; speedup vs baseline: 1.0565x; 1.0565x over previous
//
#include <hip/hip_runtime.h>

// Problem geometry: NEW_SHAPE = (16,16,512,64) flat-indexed as
//   idx = rc*32768 + i*64 + j   with rc = col*16+row, i in [0,512), j in [0,64)
//   weight element: (rc, i>>3, j); slice s = i&7 (MSB-first => shift = 14 - 2*s)
#define NELEM   (16 * 16 * 512 * 64)   // 8,388,608
#define QUARTER (NELEM / 4)            // 2,097,152

// native clang vector type — accepted by __builtin_nontemporal_load
typedef float f32x4 __attribute__((ext_vector_type(4)));

// branchless select of one lane of an f32x4 by code c in {0,1,2,3}
__device__ __forceinline__ float sel4(f32x4 v, int c) {
    return (c & 1) ? ((c & 2) ? v.w : v.y)
                   : ((c & 2) ? v.z : v.x);
}

__global__ __launch_bounds__(256) void w2g_main_kernel(
    const float*  __restrict__ input,     // (16,16,64,64) fp32, 4 MB (reused 8x, keep cached)
    const f32x4*  __restrict__ meanG,     // (NELEM,4) fp32, single-use stream
    const f32x4*  __restrict__ sigG,      // (NELEM,4) fp32, single-use stream
    const float*  __restrict__ eps,       // (NELEM) fp32, single-use stream
    const unsigned char* __restrict__ mask8,
    const unsigned int*  __restrict__ maskw,
    float* __restrict__ out)              // 4*NELEM: [Gp*am][Gn*am][Gp*!am][Gn*!am]
{
    int tid = blockIdx.x * blockDim.x + threadIdx.x;   // [0, QUARTER)

    // ---- inline mask-dtype detection (wave-uniform, first 64 words) -------
    // byte-bool mask  -> words made of bytes {0,1}: some word > 1, never 0x3F800000
    // int32 0/1 mask  -> words all <= 1
    // float 0/1 mask  -> words in {0, 0x3F800000}
    // int32 and float32 masks need the SAME test (word != 0), so only
    // byte-vs-word matters. All-zero mask: word test is also correct.
    unsigned int probe = maskw[threadIdx.x & 63];
    bool isF = (probe == 0x3F800000u);
    bool isB = (probe > 1u) && !isF;
    unsigned long long anyF = __ballot(isF);
    unsigned long long anyB = __ballot(isB);
    bool byteMode = (anyF == 0ull) && (anyB != 0ull);

    // ---- index decomposition shared by all 4 strided elements -------------
    // k*QUARTER only touches bits >= 21, so j, i, shift are k-invariant.
    int j     = tid & 63;
    int i     = (tid >> 6) & 511;
    int rc0   = tid >> 15;
    int shift = 14 - 2 * (i & 7);          // MSB-first 2-bit slice
    int ibase = ((i >> 3) << 6) | j;       // weight offset within one rc plane

#pragma unroll
    for (int k = 0; k < 4; ++k) {
        int idx = tid + k * QUARTER;
        int rc  = rc0 + (k << 6);

        float  w  = input[(rc << 12) | ibase];                     // L2/L3-resident
        f32x4  m4 = __builtin_nontemporal_load(&meanG[idx]);       // 16B coalesced
        f32x4  s4 = __builtin_nontemporal_load(&sigG[idx]);
        float  e  = __builtin_nontemporal_load(&eps[idx]);

        bool am;
        if (byteMode) am = (mask8[idx] != 0);                      // uniform branch
        else          am = (maskw[idx] != 0u);

        int wi = (int)w;                   // exact: integers in [-32767, 32767]
        int p  = wi > 0 ?  wi : 0;
        int n  = wi > 0 ?  0  : -wi;
        int cp = (p >> shift) & 3;
        int cn = (n >> shift) & 3;

        float Gp = sel4(m4, cp) + e * sel4(s4, cp);
        float Gn = sel4(m4, cn) + e * sel4(s4, cn);

        __builtin_nontemporal_store(am ? Gp : 0.0f, &out[idx]);
        __builtin_nontemporal_store(am ? Gn : 0.0f, &out[NELEM + idx]);
        __builtin_nontemporal_store(am ? 0.0f : Gp, &out[2 * NELEM + idx]);
        __builtin_nontemporal_store(am ? 0.0f : Gn, &out[3 * NELEM + idx]);
    }
}

extern "C" void kernel_launch(void* const* d_in, const int* in_sizes, int n_in,
                              void* d_out, int out_size, void* d_ws, size_t ws_size,
                              hipStream_t stream) {
    const float*  input = (const float*) d_in[0];
    const f32x4*  meanG = (const f32x4*) d_in[1];
    const f32x4*  sigG  = (const f32x4*) d_in[2];
    const float*  eps   = (const float*) d_in[3];
    const void*   mask  = d_in[4];

    int threads = 256;
    int blocks  = QUARTER / threads;       // 8192
    w2g_main_kernel<<<blocks, threads, 0, stream>>>(
        input, meanG, sigG, eps,
        (const unsigned char*)mask, (const unsigned int*)mask,
        (float*)d_out);
}